// Round 10
// baseline (1977.995 us; speedup 1.0000x reference)
//
#include <hip/hip_runtime.h>
#include <stdint.h>

#define NB 256          // batch
#define NH 1024         // hidden
#define NPOSE 135
#define NPPAD 160       // pose padded to 160
#define NSTEPS 143      // 119 encoder + 24 decoder cell steps
#define NDEC 24
#define KTOT 1184       // 1024 (h) + 160 (x padded)
#define LSTR 168        // LDS row stride for x-B chunk
#define NWG 256

typedef __bf16 bf16;
typedef __attribute__((ext_vector_type(8))) __bf16 bf16x8;
typedef __attribute__((ext_vector_type(4))) float f32x4;
typedef __attribute__((ext_vector_type(4))) uint32_t u32x4;
typedef __attribute__((ext_vector_type(2))) uint32_t u32x2;

// ---- ws layout (bytes) ----
#define WCAT_OFF 0
#define WCAT_BYTES (4096l * KTOT * 2)
#define WFC_OFF  (WCAT_OFF + WCAT_BYTES)
#define WFC_BYTES (144l * 1024 * 2)
#define X_OFF    (WFC_OFF + WFC_BYTES)
#define X_BYTES  (143l * NB * NPPAD * 2)
#define H_OFF    (X_OFF + X_BYTES)
#define H_BYTES2    (2l * NB * NH * 2)     // fallback: ping-pong
#define H_BYTES144  (144l * NB * NH * 2)   // deep: slot per step -> cacheable
#define BAR_BYTES 16384
// bar ints, one counter per 128B line:
//   cnt[bb][ch] at bar[(bb*8+ch)*32]  (h-chunk ready; +16/step: 8 WGs x 2 waves)
//   xcnt[bb]    at bar[(32+bb)*32]    (decoder X ready; +4/out-step)

__device__ __forceinline__ u32x4 llc_ld16(const void* p) {
  u32x4 v;
  asm volatile("global_load_dwordx4 %0, %1, off sc0 sc1"
               : "=v"(v) : "v"(p) : "memory");
  return v;
}
__device__ __forceinline__ u32x4 g_ld16(const void* p) {   // cached
  u32x4 v;
  asm volatile("global_load_dwordx4 %0, %1, off"
               : "=v"(v) : "v"(p) : "memory");
  return v;
}
__device__ __forceinline__ u32x4 ld16sel(const void* p, bool cached) {
  return cached ? g_ld16(p) : llc_ld16(p);
}
__device__ __forceinline__ void llc_st8(void* p, u32x2 v) {
  asm volatile("global_store_dwordx2 %0, %1, off sc0 sc1"
               :: "v"(p), "v"(v) : "memory");
}
#define WAIT_VM(n) do { \
    asm volatile("s_waitcnt vmcnt(" #n ")" ::: "memory"); \
    __builtin_amdgcn_sched_barrier(0); } while (0)

#define POLL(ptr, tgt) do { \
    while (__hip_atomic_load((ptr), __ATOMIC_RELAXED, __HIP_MEMORY_SCOPE_AGENT) < (tgt)) \
      __builtin_amdgcn_s_sleep(1); \
  } while (0)
#define POLL_SET(cidx, tgt) do { \
    for (;;) { \
      int v_ = __hip_atomic_load(&bar[(bb * 8 + (cidx)) * 32], \
                                 __ATOMIC_RELAXED, __HIP_MEMORY_SCOPE_AGENT); \
      if (__all(v_ >= (tgt))) break; \
      __builtin_amdgcn_s_sleep(1); \
    } } while (0)

__global__ void k_zero(uint32_t* p, int n) {
  int i = blockIdx.x * blockDim.x + threadIdx.x;
  int st = gridDim.x * blockDim.x;
  for (; i < n; i += st) p[i] = 0u;
}

__global__ void k_wcat(const float* __restrict__ Whh, const float* __restrict__ Wih,
                       bf16* __restrict__ W) {
  int n = blockIdx.x;
  for (int kk = threadIdx.x; kk < KTOT; kk += blockDim.x) {
    float v = 0.f;
    if (kk < NH) v = Whh[(size_t)n * NH + kk];
    else if (kk - NH < NPOSE) v = Wih[(size_t)n * NPOSE + (kk - NH)];
    W[(size_t)n * KTOT + kk] = (bf16)v;
  }
}

__global__ void k_wfc(const float* __restrict__ Wfc, bf16* __restrict__ W) {
  int p = blockIdx.x;
  for (int kk = threadIdx.x; kk < NH; kk += blockDim.x) {
    float v = (p < NPOSE) ? Wfc[(size_t)p * NH + kk] : 0.f;
    W[(size_t)p * NH + kk] = (bf16)v;
  }
}

__global__ void k_x(const float* __restrict__ poses, bf16* __restrict__ X) {
  int idx = blockIdx.x;          // t*256 + b, t in [0,120)
  int t = idx >> 8, b = idx & 255;
  int p = threadIdx.x;
  if (p < NPPAD) {
    float v = (p < NPOSE) ? poses[((size_t)b * 144 + t) * NPOSE + p] : 0.f;
    X[(size_t)idx * NPPAD + p] = (bf16)v;
  }
}

__device__ __forceinline__ float sigm(float x) { return 1.f / (1.f + __expf(-x)); }
__device__ __forceinline__ float tanh_(float x) {
  float e = __expf(2.f * x);
  return 1.f - 2.f / (e + 1.f);
}
__device__ __forceinline__ uint32_t pack2(float a, float b) {
  uint16_t lo = __builtin_bit_cast(uint16_t, (bf16)a);
  uint16_t hi = __builtin_bit_cast(uint16_t, (bf16)b);
  return ((uint32_t)hi << 16) | lo;
}

template <bool DEEP>
__global__ __launch_bounds__(256, 1) void
k_main(const float* __restrict__ poses, const float* __restrict__ bfc,
       const bf16* __restrict__ Wcat, const bf16* __restrict__ Wfcb,
       bf16* __restrict__ X, bf16* __restrict__ H, int* __restrict__ bar,
       float* __restrict__ out) {
  // W staged to LDS once (r7/r9 layout + swizzle). XCH: K-split partial exchange.
  __shared__ bf16 BldsH[8 * 64 * 128];     // 131072 B
  __shared__ bf16 BldsX[64 * LSTR];        // 21504 B
  __shared__ float XCH[2][64][20];         // 10240 B (pad 20 breaks banks)

  const int tid   = threadIdx.x;
  const int lane  = tid & 63;
  const int wv    = tid >> 6;
  const int cl    = lane & 15;
  const int quad  = lane >> 4;
  const int khalf = wv >> 1;       // 0: K-chunks 0-4; 1: chunks 5-7 + x
  const int bpair = wv & 1;        // batch tiles {bpair*32, bpair*32+16}
  const int L  = blockIdx.x;
  const int jb = (L & 7) * 8 + ((L >> 3) & 7);
  const int bb = L >> 6;
  const int b0 = bb * 64;
  const int j0 = jb * 16;
  const int mych = jb >> 3;
  const bool is_out = ((L & 7) == 7) && (((L >> 3) & 7) < 4);
  const int brow0 = bb * 64 + ((L >> 3) & 7) * 16;

  // ---- one-time W staging ----
  for (int t = tid; t < 8 * 64 * 16; t += 256) {
    int c = t >> 10, rem = t & 1023, r = rem >> 4, xb = rem & 15;
    u32x4 v = *(const u32x4*)&Wcat[(size_t)((r >> 4) * NH + j0 + (r & 15)) * KTOT
                                   + c * 128 + xb * 8];
    *(u32x4*)&BldsH[(c * 64 + r) * 128 + ((xb ^ (r & 15)) << 3)] = v;
  }
  for (int it = 0; it < 5; ++it) {
    int u = tid + it * 256, r = u / 20, iu = u % 20;
    u32x4 v = *(const u32x4*)&Wcat[(size_t)((r >> 4) * NH + j0 + (r & 15)) * KTOT
                                   + 1024 + iu * 8];
    *(u32x4*)&BldsX[r * LSTR + iu * 8] = v;
  }
  __syncthreads();

  // ---- per-lane h/x addressing (B-operand: contiguous 16B per frag) ----
  const int arow0 = b0 + bpair * 32 + cl;              // batch row, local tile 0
  const size_t hB0 = (size_t)arow0 * NH + quad * 8;    // + chn*128 + ks*32
  const size_t hB1 = hB0 + (size_t)16 * NH;            // local tile 1
  const size_t xB0 = (size_t)arow0 * NPPAD + quad * 8;
  const size_t xB1 = xB0 + (size_t)16 * NPPAD;

  u32x4 B0[8], B1[8], B2[8], BX[10];
  f32x4 acc[2][4];                 // [batch-tile][gate]
  float cst[8];
  #pragma unroll
  for (int r = 0; r < 8; ++r) cst[r] = 0.f;

#define ISSUE_B(SET, HP, chn) do { \
    const bf16* g0_ = (HP) + hB0 + (chn) * 128; \
    const bf16* g1_ = (HP) + hB1 + (chn) * 128; \
    SET[0] = ld16sel(g0_, DEEP);      SET[1] = ld16sel(g0_ + 32, DEEP); \
    SET[2] = ld16sel(g0_ + 64, DEEP); SET[3] = ld16sel(g0_ + 96, DEEP); \
    SET[4] = ld16sel(g1_, DEEP);      SET[5] = ld16sel(g1_ + 32, DEEP); \
    SET[6] = ld16sel(g1_ + 64, DEEP); SET[7] = ld16sel(g1_ + 96, DEEP); } while (0)
#define ISSUE_BX(sv) do { \
    const bf16* g0_ = X + (size_t)(sv) * NB * NPPAD + xB0; \
    const bf16* g1_ = X + (size_t)(sv) * NB * NPPAD + xB1; \
    if ((sv) < 120) { \
      _Pragma("unroll") \
      for (int k_ = 0; k_ < 5; ++k_) { BX[k_] = g_ld16(g0_ + k_ * 32); \
                                       BX[5 + k_] = g_ld16(g1_ + k_ * 32); } \
    } else { \
      _Pragma("unroll") \
      for (int k_ = 0; k_ < 5; ++k_) { BX[k_] = ld16sel(g0_ + k_ * 32, DEEP); \
                                       BX[5 + k_] = ld16sel(g1_ + k_ * 32, DEEP); } \
    } } while (0)
// TRANSPOSED: W-frag is operand A, h-frag is operand B.
// acc[bt][gt][r] = gates[gcol = gt*16 + quad*4 + r][brow = bt*16-local + cl]
#define MFMA_H(SET, c) do { \
    _Pragma("unroll") \
    for (int ks = 0; ks < 4; ++ks) { \
      bf16x8 h0_ = __builtin_bit_cast(bf16x8, SET[ks]); \
      bf16x8 h1_ = __builtin_bit_cast(bf16x8, SET[4 + ks]); \
      _Pragma("unroll") \
      for (int gt = 0; gt < 4; ++gt) { \
        bf16x8 wf_ = *(const bf16x8*)&BldsH[((c) * 64 + gt * 16 + cl) * 128 \
                                            + (((ks * 4 + quad) ^ cl) << 3)]; \
        acc[0][gt] = __builtin_amdgcn_mfma_f32_16x16x32_bf16(wf_, h0_, acc[0][gt], 0, 0, 0); \
        acc[1][gt] = __builtin_amdgcn_mfma_f32_16x16x32_bf16(wf_, h1_, acc[1][gt], 0, 0, 0); \
      } } } while (0)
#define MFMA_X() do { \
    _Pragma("unroll") \
    for (int ks = 0; ks < 5; ++ks) { \
      bf16x8 h0_ = __builtin_bit_cast(bf16x8, BX[ks]); \
      bf16x8 h1_ = __builtin_bit_cast(bf16x8, BX[5 + ks]); \
      _Pragma("unroll") \
      for (int gt = 0; gt < 4; ++gt) { \
        bf16x8 wf_ = *(const bf16x8*)&BldsX[(gt * 16 + cl) * LSTR + ks * 32 + quad * 8]; \
        acc[0][gt] = __builtin_amdgcn_mfma_f32_16x16x32_bf16(wf_, h0_, acc[0][gt], 0, 0, 0); \
        acc[1][gt] = __builtin_amdgcn_mfma_f32_16x16x32_bf16(wf_, h1_, acc[1][gt], 0, 0, 0); \
      } } } while (0)

  // ---- prologue: step-0 first two chunks per K-half (h(0)=zeros, slot 0) ----
  if (khalf == 0) { ISSUE_B(B0, H, 0); ISSUE_B(B1, H, 1); }
  else            { ISSUE_B(B0, H, 5); ISSUE_B(B1, H, 6); }

  for (int s = 0; s < NSTEPS; ++s) {
    const bf16* Hr = H + (size_t)(DEEP ? s : (s & 1)) * (NB * NH);
    bf16* Hw = H + (size_t)(DEEP ? (s + 1) : ((s + 1) & 1)) * (NB * NH);
    #pragma unroll
    for (int bt = 0; bt < 2; ++bt)
      #pragma unroll
      for (int gt = 0; gt < 4; ++gt) acc[bt][gt] = f32x4{0, 0, 0, 0};

    if (khalf == 0) {          // chunks 0-4
      ISSUE_B(B2, Hr, 2); WAIT_VM(16); MFMA_H(B0, 0);
      ISSUE_B(B0, Hr, 3); WAIT_VM(16); MFMA_H(B1, 1);
      ISSUE_B(B1, Hr, 4); WAIT_VM(16); MFMA_H(B2, 2);
                          WAIT_VM(8);  MFMA_H(B0, 3);
                          WAIT_VM(0);  MFMA_H(B1, 4);
    } else {                   // chunks 5-7 + x
      ISSUE_B(B2, Hr, 7); WAIT_VM(16); MFMA_H(B0, 5);
      if (s >= 120) POLL(&bar[(32 + bb) * 32], 4 * (s - 119));
      ISSUE_BX(s);        WAIT_VM(18); MFMA_H(B1, 6);
                          WAIT_VM(10); MFMA_H(B2, 7);
                          WAIT_VM(0);  MFMA_X();
      #pragma unroll
      for (int gt = 0; gt < 4; ++gt)               // round-1 partials (tile 0)
        *(f32x4*)&XCH[bpair][lane][gt * 4] = acc[0][gt];
    }
    __syncthreads();                               // b1: round-1 visible
    if (khalf == 0) {
      #pragma unroll
      for (int gt = 0; gt < 4; ++gt)
        acc[0][gt] += *(const f32x4*)&XCH[bpair][lane][gt * 4];
    }
    __syncthreads();                               // b2: round-1 consumed
    if (khalf == 1) {
      #pragma unroll
      for (int gt = 0; gt < 4; ++gt)               // round-2 partials (tile 1)
        *(f32x4*)&XCH[bpair][lane][gt * 4] = acc[1][gt];
    }
    __syncthreads();                               // b3: round-2 visible
    if (khalf == 0) {
      #pragma unroll
      for (int gt = 0; gt < 4; ++gt)
        acc[1][gt] += *(const f32x4*)&XCH[bpair][lane][gt * 4];
    }
    __syncthreads();                               // b4: XCH free; w23 may run ahead

    if (khalf == 0) {
      // ---- activation: all 4 gates in-lane; 1 contiguous 8B store per tile ----
      #pragma unroll
      for (int bt = 0; bt < 2; ++bt) {
        float hv[4];
        #pragma unroll
        for (int r = 0; r < 4; ++r) {
          float iv = acc[bt][0][r], fv = acc[bt][1][r];
          float gv = acc[bt][2][r], ov = acc[bt][3][r];
          float cn = sigm(fv) * cst[bt * 4 + r] + sigm(iv) * tanh_(gv);
          cst[bt * 4 + r] = cn;
          hv[r] = sigm(ov) * tanh_(cn);
        }
        u32x2 pk; pk[0] = pack2(hv[0], hv[1]); pk[1] = pack2(hv[2], hv[3]);
        llc_st8(&Hw[(size_t)(arow0 + bt * 16) * NH + j0 + quad * 4], pk);
      }
      WAIT_VM(0);                                  // h rows acked at LLC
      if (lane == 0) atomicAdd(&bar[(bb * 8 + mych) * 32], 1);   // +2 per WG
    }

    if (s >= 119 && is_out) {   // decoder: out = inp + h_new @ W_fc^T + b_fc
      const int k = s - 119;
      POLL_SET(lane & 7, 16 * (s + 1));            // full h(s+1) ready
      f32x4 oa[3] = {{0,0,0,0},{0,0,0,0},{0,0,0,0}};
      const bf16* hrow = Hw + (size_t)(brow0 + cl) * NH;
      for (int kb = 0; kb < 4; ++kb) {
        u32x4 hv[8];
        #pragma unroll
        for (int t = 0; t < 8; ++t)
          hv[t] = ld16sel(&hrow[(kb * 8 + t) * 32 + quad * 8], DEEP);
        WAIT_VM(0);
        #pragma unroll
        for (int t = 0; t < 8; ++t) {
          bf16x8 af = __builtin_bit_cast(bf16x8, hv[t]);
          #pragma unroll
          for (int i = 0; i < 3; ++i) {
            int ct = wv + i * 4;
            if (ct > 8) continue;
            bf16x8 bw = *(const bf16x8*)&Wfcb[(size_t)(ct * 16 + cl) * NH
                                              + (kb * 8 + t) * 32 + quad * 8];
            oa[i] = __builtin_amdgcn_mfma_f32_16x16x32_bf16(af, bw, oa[i], 0, 0, 0);
          }
        }
      }
      #pragma unroll
      for (int i = 0; i < 3; ++i) {
        int ct = wv + i * 4;
        if (ct > 8) continue;
        int p = ct * 16 + cl;
        if (p < NPOSE) {
          #pragma unroll
          for (int r = 0; r < 4; ++r) {
            int b = brow0 + quad * 4 + r;
            float inp = (k == 0) ? poses[((size_t)b * 144 + 119) * NPOSE + p]
                                 : out[((size_t)b * NDEC + (k - 1)) * NPOSE + p];
            float v = oa[i][r] + inp + bfc[p];       // additive chain kept fp32
            out[((size_t)b * NDEC + k) * NPOSE + p] = v;
            if (s + 1 < NSTEPS) {
              bf16 xb = (bf16)v;
              asm volatile("global_store_short %0, %1, off sc0 sc1"
                           :: "v"(&X[((size_t)(s + 1) * NB + b) * NPPAD + p]),
                              "v"((uint32_t)__builtin_bit_cast(uint16_t, xb)) : "memory");
            }
          }
        }
      }
      if (s + 1 < NSTEPS) {
        WAIT_VM(0);
        __syncthreads();
        if (tid == 0) atomicAdd(&bar[(32 + bb) * 32], 1);
      }
    }

    // ---- tail: per-half readiness poll, then prefetch step s+1 ----
    if (s + 1 < NSTEPS) {
      bf16* Hn = H + (size_t)(DEEP ? (s + 1) : ((s + 1) & 1)) * (NB * NH);
      if (khalf == 0) {
        int c = lane & 7; if (c > 4) c = 0;
        POLL_SET(c, 16 * (s + 1));
        ISSUE_B(B0, Hn, 0); ISSUE_B(B1, Hn, 1);
      } else {
        int c = 5 + (lane % 3);
        POLL_SET(c, 16 * (s + 1));
        ISSUE_B(B0, Hn, 5); ISSUE_B(B1, Hn, 6);
      }
    }
  }
}

extern "C" void kernel_launch(void* const* d_in, const int* in_sizes, int n_in,
                              void* d_out, int out_size, void* d_ws, size_t ws_size,
                              hipStream_t stream) {
  const float* poses = (const float*)d_in[0];
  const float* Wih   = (const float*)d_in[1];
  const float* Whh   = (const float*)d_in[2];
  const float* Wfc   = (const float*)d_in[3];
  const float* bfc   = (const float*)d_in[4];

  const size_t need_deep = (size_t)H_OFF + H_BYTES144 + BAR_BYTES;
  const size_t need_min  = (size_t)H_OFF + H_BYTES2 + BAR_BYTES;
  if (ws_size < need_min) return;
  const bool deep = ws_size >= need_deep;
  const size_t hbytes = deep ? (size_t)H_BYTES144 : (size_t)H_BYTES2;

  char* ws = (char*)d_ws;
  bf16* Wcat = (bf16*)(ws + WCAT_OFF);
  bf16* Wfcb = (bf16*)(ws + WFC_OFF);
  bf16* X    = (bf16*)(ws + X_OFF);
  bf16* H    = (bf16*)(ws + H_OFF);
  int*  bar  = (int*)(ws + H_OFF + hbytes);

  if (deep) {
    k_zero<<<256, 256, 0, stream>>>((uint32_t*)(ws + H_OFF), (int)(NB * NH * 2 / 4));
    k_zero<<<32, 256, 0, stream>>>((uint32_t*)bar, BAR_BYTES / 4);
  } else {
    k_zero<<<256, 256, 0, stream>>>((uint32_t*)(ws + H_OFF),
                                    (int)((H_BYTES2 + BAR_BYTES) / 4));
  }
  k_zero<<<256, 256, 0, stream>>>((uint32_t*)(X + (size_t)120 * NB * NPPAD),
                                  (int)(23l * NB * NPPAD * 2 / 4));
  k_wcat<<<4096, 256, 0, stream>>>(Whh, Wih, Wcat);
  k_wfc<<<144, 256, 0, stream>>>(Wfc, Wfcb);
  k_x<<<120 * 256, 256, 0, stream>>>(poses, X);
  if (deep)
    k_main<true><<<NWG, 256, 0, stream>>>(poses, bfc, Wcat, Wfcb, X, H, bar,
                                          (float*)d_out);
  else
    k_main<false><<<NWG, 256, 0, stream>>>(poses, bfc, Wcat, Wfcb, X, H, bar,
                                           (float*)d_out);
}